// Round 1
// baseline (86.343 us; speedup 1.0000x reference)
//
#include <hip/hip_runtime.h>
#include <math.h>

#define BB 128   // batch
#define VV 4     // views
#define NN 512   // BB*VV rows
#define DD 128   // feature dim

// ---------------------------------------------------------------------------
// Kernel 1: L2-normalize each embedding row; emit sq_norm (post-normalization,
// matching the reference's sum(emb*emb)); block 0 zeros the accumulators.
// emb row i = v*BB + b  maps to  features[b, v, :]  (b = i % BB, v = i / BB).
// ---------------------------------------------------------------------------
__global__ __launch_bounds__(64)
void normalize_kernel(const float* __restrict__ feat,
                      float* __restrict__ emb,
                      float* __restrict__ sqn,
                      float* __restrict__ gsum,
                      unsigned int* __restrict__ gcnt) {
    int i = blockIdx.x;        // row in [0, NN)
    int tid = threadIdx.x;     // 0..63
    if (i == 0 && tid == 0) { *gsum = 0.f; *gcnt = 0u; }

    int b = i & (BB - 1);
    int v = i >> 7;
    const float* src = feat + (size_t)b * (VV * DD) + (size_t)v * DD;

    float x0 = src[tid];
    float x1 = src[tid + 64];
    float ss = x0 * x0 + x1 * x1;
    #pragma unroll
    for (int off = 32; off > 0; off >>= 1) ss += __shfl_xor(ss, off);

    float inv = 1.f / fmaxf(sqrtf(ss), 1e-12f);
    float y0 = x0 * inv, y1 = x1 * inv;
    emb[i * DD + tid]      = y0;
    emb[i * DD + tid + 64] = y1;

    float s2 = y0 * y0 + y1 * y1;
    #pragma unroll
    for (int off = 32; off > 0; off >>= 1) s2 += __shfl_xor(s2, off);
    if (tid == 0) sqn[i] = s2;
}

// ---------------------------------------------------------------------------
// Kernel 2: one block per anchor. Compute the anchor's distance row, split
// into positive / negative distance lists, then reduce relu(d_ap - d_an)
// sum + nonzero count over all valid (p, n) pairs.
// ---------------------------------------------------------------------------
__global__ __launch_bounds__(256)
void triplet_kernel(const float* __restrict__ emb,
                    const float* __restrict__ sqn,
                    const int* __restrict__ labels,
                    float* __restrict__ gsum,
                    unsigned int* __restrict__ gcnt) {
    __shared__ float s_anchor[DD];
    __shared__ float s_d[NN];
    __shared__ int   s_lab[BB];
    __shared__ float s_pos[NN];
    __shared__ float s_neg[NN];
    __shared__ int   s_np, s_nn;
    __shared__ float s_wsum[4];
    __shared__ unsigned int s_wcnt[4];

    int a   = blockIdx.x;
    int tid = threadIdx.x;   // 0..255

    if (tid < DD) s_anchor[tid] = emb[a * DD + tid];
    if (tid < BB) s_lab[tid] = labels[tid];
    if (tid == 0) { s_np = 0; s_nn = 0; }
    __syncthreads();

    float sa = sqn[a];
    // distance row: each thread handles 2 of the 512 columns
    for (int j = tid; j < NN; j += 256) {
        const float4* row4 = (const float4*)(emb + j * DD);
        const float4* anc4 = (const float4*)s_anchor;
        float dot = 0.f;
        #pragma unroll
        for (int k = 0; k < DD / 4; ++k) {
            float4 r = row4[k];
            float4 c = anc4[k];
            dot = fmaf(r.x, c.x, dot);
            dot = fmaf(r.y, c.y, dot);
            dot = fmaf(r.z, c.z, dot);
            dot = fmaf(r.w, c.w, dot);
        }
        float sq = fmaxf(sa + sqn[j] - 2.f * dot, 0.f);
        s_d[j] = (sq > 0.f) ? sqrtf(sq) : 0.f;   // safe_sqrt semantics
    }
    __syncthreads();

    // partition into positives (same label, j != a) and negatives
    int la = s_lab[a & (BB - 1)];
    for (int j = tid; j < NN; j += 256) {
        float dj = s_d[j];
        if (s_lab[j & (BB - 1)] == la) {
            if (j != a) s_pos[atomicAdd(&s_np, 1)] = dj;
        } else {
            s_neg[atomicAdd(&s_nn, 1)] = dj;
        }
    }
    __syncthreads();

    int np = s_np, nn = s_nn;
    int total = np * nn;
    float lsum = 0.f;
    unsigned int lcnt = 0;
    for (int k = tid; k < total; k += 256) {
        int p = k / nn;
        int n = k - p * nn;
        float diff = s_pos[p] - s_neg[n];
        if (diff > 0.f) { lsum += diff; lcnt++; }
    }

    // wave reduce (64 lanes) then cross-wave via LDS
    #pragma unroll
    for (int off = 32; off > 0; off >>= 1) {
        lsum += __shfl_down(lsum, off);
        lcnt += __shfl_down(lcnt, off);
    }
    int wave = tid >> 6, lane = tid & 63;
    if (lane == 0) { s_wsum[wave] = lsum; s_wcnt[wave] = lcnt; }
    __syncthreads();
    if (tid == 0) {
        atomicAdd(gsum, s_wsum[0] + s_wsum[1] + s_wsum[2] + s_wsum[3]);
        atomicAdd(gcnt, s_wcnt[0] + s_wcnt[1] + s_wcnt[2] + s_wcnt[3]);
    }
}

// ---------------------------------------------------------------------------
// Kernel 3: final scalar
// ---------------------------------------------------------------------------
__global__ void finalize_kernel(const float* __restrict__ gsum,
                                const unsigned int* __restrict__ gcnt,
                                float* __restrict__ out) {
    unsigned int c = *gcnt;
    out[0] = (c > 0u) ? (*gsum) / (float)c : 0.f;
}

extern "C" void kernel_launch(void* const* d_in, const int* in_sizes, int n_in,
                              void* d_out, int out_size, void* d_ws, size_t ws_size,
                              hipStream_t stream) {
    const float* feat   = (const float*)d_in[0];   // [128, 4, 128] fp32
    const int*   labels = (const int*)d_in[1];     // [128] int32
    float* out = (float*)d_out;

    char* ws = (char*)d_ws;
    float*        emb  = (float*)ws;                                   // NN*DD floats
    float*        sqn  = (float*)(ws + (size_t)NN * DD * sizeof(float));
    float*        gsum = (float*)(ws + (size_t)(NN * DD + NN) * sizeof(float));
    unsigned int* gcnt = (unsigned int*)(ws + (size_t)(NN * DD + NN + 1) * sizeof(float));

    normalize_kernel<<<NN, 64, 0, stream>>>(feat, emb, sqn, gsum, gcnt);
    triplet_kernel<<<NN, 256, 0, stream>>>(emb, sqn, labels, gsum, gcnt);
    finalize_kernel<<<1, 1, 0, stream>>>(gsum, gcnt, out);
}